// Round 2
// baseline (926.972 us; speedup 1.0000x reference)
//
#include <hip/hip_runtime.h>
#include <hip/hip_bf16.h>

typedef unsigned short u16;
typedef unsigned int u32;
typedef __attribute__((ext_vector_type(4))) float f32x4;
typedef __attribute__((ext_vector_type(8))) short s16x8;

#define NHEADS 16
#define TSEQ 2048
#define BATCH 4
#define BT (BATCH*TSEQ)   // 8192 rows

__device__ __forceinline__ float bf2f(u16 v){ u32 u=((u32)v)<<16; return __builtin_bit_cast(float,u); }
__device__ __forceinline__ u16 f2bf(float f){ u32 u=__builtin_bit_cast(u32,f); u += 0x7fffu + ((u>>16)&1u); return (u16)(u>>16); }

__device__ __forceinline__ void gload16(const void* g, void* l){
  __builtin_amdgcn_global_load_lds((const __attribute__((address_space(1))) u32*)g,
                                   (__attribute__((address_space(3))) u32*)l, 16, 0, 0);
}

// ---------------- cast fp32 -> bf16 (vectorized) ----------------
__global__ void cast_bf16_kernel(const float* __restrict__ in, u16* __restrict__ out, long n){
  long i = ((long)blockIdx.x*256 + threadIdx.x)*4;
  if (i >= n) return;
  float4 v = *(const float4*)(in + i);
  ushort4 o;
  o.x = f2bf(v.x); o.y = f2bf(v.y); o.z = f2bf(v.z); o.w = f2bf(v.w);
  *(ushort4*)(out + i) = o;
}

// ---------------- transpose+cast: in[R][C] f32 -> out[C][R] bf16 ----------------
__global__ void transpose_cast_kernel(const float* __restrict__ in, u16* __restrict__ out, int R, int C){
  __shared__ float tile[32][33];
  int bc = blockIdx.x*32, br = blockIdx.y*32;
  int lx = threadIdx.x & 31, ly = threadIdx.x >> 5;   // 32x8
  #pragma unroll
  for (int i=0;i<32;i+=8)
    tile[ly+i][lx] = in[(long)(br+ly+i)*C + bc + lx];
  __syncthreads();
  #pragma unroll
  for (int i=0;i<32;i+=8)
    out[(long)(bc+ly+i)*R + br + lx] = f2bf(tile[lx][ly+i]);
}

// ---------------- RoPE tables: ctab/stab[t][32] ----------------
__global__ void rope_tab_kernel(float* __restrict__ ctab, float* __restrict__ stab){
  int idx = blockIdx.x*256 + threadIdx.x;   // 65536 = 2048*32
  int t = idx >> 5, i = idx & 31;
  // theta = 10000^(-i/32)
  float theta = expf(-(float)i * (9.210340371976184f/32.0f));
  float ang = (float)t * theta;
  float s, c;
  sincosf(ang, &s, &c);
  ctab[idx] = c; stab[idx] = s;
}

// ---------------- RoPE in place: buf rows of (1<<log2ppr) u32-pairs, 32 pairs per head ----------------
__global__ void rope_inplace_kernel(u32* __restrict__ buf, const float* __restrict__ ct,
                                    const float* __restrict__ st, int log2ppr){
  long idx = (long)blockIdx.x*256 + threadIdx.x;   // total pairs = BT << log2ppr
  long row = idx >> log2ppr;
  int pp = (int)(idx & ((1<<log2ppr)-1));
  int t = (int)(row & (TSEQ-1));
  int pr = pp & 31;
  u32 v = buf[idx];
  float x0 = bf2f((u16)v), x1 = bf2f((u16)(v>>16));
  float c = ct[t*32+pr], s = st[t*32+pr];
  float y0 = x0*c - x1*s;
  float y1 = x1*c + x0*s;
  buf[idx] = (u32)f2bf(y0) | ((u32)f2bf(y1)<<16);
}

// ---------------- GEMM: C[M][N] = A[M][K](bf16,lda) @ Bt[N][K]^T(bf16,ldb) + bias ----------------
// m97 structure: 128x128 tile, BK=32, 4 waves each 64x64, global_load_lds width 16.
template<int OUTF32>
__global__ __launch_bounds__(256,2) void gemm_bt_kernel(
    const u16* __restrict__ A, const u16* __restrict__ Bt, const float* __restrict__ bias,
    void* __restrict__ Cp, int M, int N, int K, int lda, int ldb, int ldc)
{
  __shared__ u16 As[128*32];
  __shared__ u16 Bs[128*32];
  const int tid = threadIdx.x;
  const int lane = tid & 63;
  const int wave = tid >> 6;
  const long bm = (long)blockIdx.x * 128;
  const long bn = (long)blockIdx.y * 128;
  const int wr = (wave>>1)*64, wc = (wave&1)*64;
  const int g = lane>>4, r15 = lane&15;

  f32x4 acc[4][4];
  #pragma unroll
  for (int m=0;m<4;m++)
    #pragma unroll
    for (int n=0;n<4;n++) acc[m][n] = (f32x4){0.f,0.f,0.f,0.f};

  // staging: 512 chunks of 16B per tile; thread handles chunks tid and tid+256.
  const int c0 = tid, c1 = tid + 256;
  const u16* gA0 = A + (bm + (c0>>2))*lda + (c0&3)*8;
  const u16* gA1 = A + (bm + (c1>>2))*lda + (c1&3)*8;
  const u16* gB0 = Bt + (bn + (c0>>2))*ldb + (c0&3)*8;
  const u16* gB1 = Bt + (bn + (c1>>2))*ldb + (c1&3)*8;
  u16* lA0 = As + c0*8;
  u16* lA1 = As + c1*8;
  u16* lB0 = Bs + c0*8;
  u16* lB1 = Bs + c1*8;

  for (int k0 = 0; k0 < K; k0 += 32) {
    __syncthreads();
    gload16(gA0 + k0, lA0);
    gload16(gA1 + k0, lA1);
    gload16(gB0 + k0, lB0);
    gload16(gB1 + k0, lB1);
    __syncthreads();   // compiler drains vmcnt before s_barrier
    s16x8 af[4], bfr[4];
    #pragma unroll
    for (int m=0;m<4;m++) af[m] = *(const s16x8*)(As + (wr + m*16 + r15)*32 + g*8);
    #pragma unroll
    for (int n=0;n<4;n++) bfr[n] = *(const s16x8*)(Bs + (wc + n*16 + r15)*32 + g*8);
    #pragma unroll
    for (int m=0;m<4;m++)
      #pragma unroll
      for (int n=0;n<4;n++)
        acc[m][n] = __builtin_amdgcn_mfma_f32_16x16x32_bf16(af[m], bfr[n], acc[m][n], 0,0,0);
  }

  // epilogue: C/D layout col=lane&15, row=(lane>>4)*4+i
  #pragma unroll
  for (int n=0;n<4;n++){
    long col = bn + wc + n*16 + r15;
    if (col >= N) continue;
    float bv = bias[col];
    #pragma unroll
    for (int m=0;m<4;m++){
      long row0 = bm + wr + m*16 + g*4;
      #pragma unroll
      for (int i=0;i<4;i++){
        long row = row0 + i;
        if (row < M){
          float v = acc[m][n][i] + bv;
          if (OUTF32) ((float*)Cp)[row*(long)ldc + col] = v;
          else        ((u16*)Cp)[row*(long)ldc + col] = f2bf(v);
        }
      }
    }
  }
}

// ---------------- Vt[bh][d][t] = vk_b[b,t,h*256+d] (transpose via LDS) ----------------
__global__ void transpose_v_kernel(const u16* __restrict__ vk_b, u16* __restrict__ Vt){
  __shared__ u16 tile[128][130];
  int t0 = blockIdx.x*128;
  int bh = blockIdx.y;
  int b = bh>>4, h = bh&15;
  for (int idx = threadIdx.x; idx < 128*128; idx += 256){
    int r = idx>>7, c = idx&127;
    tile[r][c] = vk_b[((long)(b*TSEQ + t0 + r))*4096 + h*256 + c];
  }
  __syncthreads();
  for (int idx = threadIdx.x; idx < 128*128; idx += 256){
    int d = idx>>7, tt = idx&127;
    Vt[((long)bh*128 + d)*TSEQ + t0 + tt] = tile[tt][d];
  }
}

// ---------------- flash attention (non-causal), 4 waves x 16 q-rows, K-tile=64 ----------------
// Reads q_b [bt][h*128+d], roped qr_b [bt][h*64+d], vk_b (k-part), roped kr_b [bt][64], Vt [bh][d][t].
__global__ __launch_bounds__(256,2) void attn_kernel(
    const u16* __restrict__ q_b, const u16* __restrict__ qr_b,
    const u16* __restrict__ vk_b, const u16* __restrict__ kr_b,
    const u16* __restrict__ Vt, u16* __restrict__ attn_b)
{
  __shared__ u16 Ks[64*192];    // swizzled: byte ^= (row&7)<<4
  __shared__ u16 Vs[128*64];    // swizzled
  __shared__ u16 Ps[4][16*64];  // per-wave, swizzled

  const int tid = threadIdx.x;
  const int lane = tid & 63;
  const int wave = tid >> 6;
  const int g = lane >> 4;
  const int r15 = lane & 15;
  const int bh = blockIdx.y;
  const int b = bh>>4, h = bh&15;
  const int q0 = blockIdx.x*64 + wave*16;

  // Q fragments hoisted to registers (A-operand: row=lane&15, k=(lane>>4)*8..+7)
  s16x8 qf[6];
  {
    const u16* qp  = q_b  + ((long)b*TSEQ + q0 + r15)*2048 + h*128 + g*8;
    const u16* qrp = qr_b + ((long)b*TSEQ + q0 + r15)*1024 + h*64  + g*8;
    #pragma unroll
    for (int kd=0;kd<4;kd++) qf[kd] = *(const s16x8*)(qp + kd*32);
    #pragma unroll
    for (int kd=4;kd<6;kd++) qf[kd] = *(const s16x8*)(qrp + (kd-4)*32);
  }

  f32x4 oacc[8];
  #pragma unroll
  for (int i=0;i<8;i++) oacc[i] = (f32x4){0.f,0.f,0.f,0.f};
  float mrow[4] = {-__builtin_inff(),-__builtin_inff(),-__builtin_inff(),-__builtin_inff()};
  float lrow[4] = {0.f,0.f,0.f,0.f};

  const int krow_s = tid>>2;   // K staging: 4 threads/row, 6 chunks each
  const int kslot_s = tid&3;
  const int vrow_s = tid>>1;   // V staging: 2 threads/row, 4 chunks each
  const int vslot_s = tid&1;
  const u16* kbase = vk_b + (long)b*TSEQ*4096 + h*256 + 128 + kslot_s*8;   // + t*4096
  const u16* rbase = kr_b + (long)b*TSEQ*64 + kslot_s*8;                   // + t*64
  const long vg_base = (long)bh*128*TSEQ;
  char* KsB = (char*)Ks;
  char* VsB = (char*)Vs;
  char* PsB = (char*)(&Ps[wave][0]);

  for (int kt=0; kt<32; ++kt) {
    __syncthreads();
    { // stage K tile (64x[128|64]) and V tile (128x64) with XOR swizzle
      long t = (long)(kt*64 + krow_s);
      u32 base = (u32)((krow_s*24 + kslot_s)*16);
      u32 sw = (u32)((krow_s&7)<<4);
      #pragma unroll
      for (int j=0;j<4;j++){
        s16x8 v = *(const s16x8*)(kbase + t*4096 + j*32);
        *(s16x8*)(KsB + ((base + j*64) ^ sw)) = v;
      }
      #pragma unroll
      for (int j=4;j<6;j++){
        s16x8 v = *(const s16x8*)(rbase + t*64 + (j-4)*32);
        *(s16x8*)(KsB + ((base + j*64) ^ sw)) = v;
      }
      const u16* vsrc = Vt + vg_base + (long)vrow_s*TSEQ + kt*64 + vslot_s*8;
      u32 vbase = (u32)((vrow_s*8 + vslot_s)*16);
      u32 vsw = (u32)((vrow_s&7)<<4);
      #pragma unroll
      for (int j=0;j<4;j++){
        s16x8 v = *(const s16x8*)(vsrc + j*16);
        *(s16x8*)(VsB + ((vbase + j*32) ^ vsw)) = v;
      }
    }
    __syncthreads();

    // S = Q @ K^T  (16 q-rows x 64 keys)
    f32x4 sacc[4];
    #pragma unroll
    for (int n=0;n<4;n++) sacc[n] = (f32x4){0.f,0.f,0.f,0.f};
    #pragma unroll
    for (int kd=0; kd<6; kd++){
      #pragma unroll
      for (int n=0;n<4;n++){
        int krow = n*16 + r15;
        u32 byt = (u32)(krow*384 + kd*64 + g*16) ^ (u32)((krow&7)<<4);
        s16x8 kfr = *(const s16x8*)(KsB + byt);
        sacc[n] = __builtin_amdgcn_mfma_f32_16x16x32_bf16(qf[kd], kfr, sacc[n], 0,0,0);
      }
    }

    const float scale = 0.08838834764831845f;  // 1/sqrt(128)
    float tmax[4];
    #pragma unroll
    for (int i=0;i<4;i++){
      float m0 = fmaxf(fmaxf(sacc[0][i],sacc[1][i]), fmaxf(sacc[2][i],sacc[3][i]));
      #pragma unroll
      for (int off=1; off<16; off<<=1) m0 = fmaxf(m0, __shfl_xor(m0, off));
      tmax[i] = m0*scale;
    }
    float psc[4];
    #pragma unroll
    for (int i=0;i<4;i++){
      float mn = fmaxf(mrow[i], tmax[i]);
      psc[i] = __expf(mrow[i]-mn);
      mrow[i] = mn;
    }
    float rs[4] = {0.f,0.f,0.f,0.f};
    #pragma unroll
    for (int n=0;n<4;n++){
      #pragma unroll
      for (int i=0;i<4;i++){
        float p = __expf(sacc[n][i]*scale - mrow[i]);
        rs[i] += p;
        int prow = g*4+i;
        u32 pb = (u32)(prow*128 + (n*16+r15)*2) ^ (u32)((prow&7)<<4);
        *(u16*)(PsB + pb) = f2bf(p);
      }
    }
    #pragma unroll
    for (int i=0;i<4;i++){
      float rsum = rs[i];
      #pragma unroll
      for (int off=1; off<16; off<<=1) rsum += __shfl_xor(rsum, off);
      lrow[i] = lrow[i]*psc[i] + rsum;
    }
    #pragma unroll
    for (int nf=0;nf<8;nf++){
      f32x4 o = oacc[nf];
      o[0]*=psc[0]; o[1]*=psc[1]; o[2]*=psc[2]; o[3]*=psc[3];
      oacc[nf] = o;
    }
    // O += P @ V   (P from per-wave LDS, V B-operand from swizzled LDS)
    #pragma unroll
    for (int ks=0; ks<2; ks++){
      u32 pb = (u32)(r15*128 + ks*64 + g*16) ^ (u32)((r15&7)<<4);
      s16x8 pf = *(const s16x8*)(PsB + pb);
      #pragma unroll
      for (int nf=0;nf<8;nf++){
        int vrow = nf*16 + r15;
        u32 vb = (u32)(vrow*128 + ks*64 + g*16) ^ (u32)((vrow&7)<<4);
        s16x8 vf = *(const s16x8*)(VsB + vb);
        oacc[nf] = __builtin_amdgcn_mfma_f32_16x16x32_bf16(pf, vf, oacc[nf], 0,0,0);
      }
    }
  }

  // epilogue: attn_b[(b*T+t)][h*128+d]
  #pragma unroll
  for (int nf=0;nf<8;nf++){
    #pragma unroll
    for (int i=0;i<4;i++){
      float v = oacc[nf][i] / lrow[i];
      long t = q0 + g*4 + i;
      attn_b[((long)b*TSEQ + t)*2048 + h*128 + nf*16 + r15] = f2bf(v);
    }
  }
}

extern "C" void kernel_launch(void* const* d_in, const int* in_sizes, int n_in,
                              void* d_out, int out_size, void* d_ws, size_t ws_size,
                              hipStream_t stream)
{
  const float* x      = (const float*)d_in[0];
  const float* W_down = (const float*)d_in[1];
  const float* b_down = (const float*)d_in[2];
  const float* W_uKV  = (const float*)d_in[3];
  const float* b_uKV  = (const float*)d_in[4];
  const float* W_uQ   = (const float*)d_in[5];
  const float* b_uQ   = (const float*)d_in[6];
  const float* W_kr   = (const float*)d_in[7];
  const float* b_kr   = (const float*)d_in[8];
  const float* W_qr   = (const float*)d_in[9];
  const float* b_qr   = (const float*)d_in[10];
  const float* W_out  = (const float*)d_in[11];
  const float* b_out  = (const float*)d_in[12];
  float* out = (float*)d_out;

  char* ws = (char*)d_ws;
  size_t off = 0;
  auto alloc = [&](size_t b)->char* { char* p = ws + off; off += (b + 255) & ~(size_t)255; return p; };

  // Arena (~200 MiB) with lifetime aliasing:
  //  slot0: xb (x bf16) -> dead after projection GEMMs -> reused as attn_b
  //  slot5: down_b -> dead after uKV/uQ GEMMs -> reused as Vt
  u16* xb     = (u16*)alloc((size_t)BT*2048*2);      // 33.5 MB
  u16* attn_b = xb;                                   // alias (xb dead by attn)
  u16* q_b    = (u16*)alloc((size_t)BT*2048*2);      // 33.5 MB
  u16* vk_b   = (u16*)alloc((size_t)BT*4096*2);      // 67.1 MB
  u16* qr_b   = (u16*)alloc((size_t)BT*1024*2);      // 16.8 MB (roped in place)
  u16* kr_b   = (u16*)alloc((size_t)BT*64*2);        // 1.05 MB (roped in place)
  char* slot5 = alloc((size_t)64*128*TSEQ*2);        // 33.5 MB
  u16* down_b = (u16*)slot5;                         // [8192][1024], first occupant
  u16* Vt     = (u16*)slot5;                         // [bh][128][2048], second occupant
  u16* Wd_t   = (u16*)alloc((size_t)1024*2048*2);
  u16* Wqr_t  = (u16*)alloc((size_t)1024*2048*2);
  u16* Wkr_t  = (u16*)alloc((size_t)128*2048*2);     // padded 64->128 rows
  u16* WuKV_t = (u16*)alloc((size_t)4096*512*2);
  u16* WuQ_t  = (u16*)alloc((size_t)2048*512*2);
  u16* Wout_t = (u16*)alloc((size_t)2048*2048*2);
  float* ctab = (float*)alloc((size_t)2048*32*4);
  float* stab = (float*)alloc((size_t)2048*32*4);
  // total = 209,715,200 B = 200.0 MiB

  // 1) casts + transposes + tables
  long nx = (long)BT*2048;
  cast_bf16_kernel<<<dim3((u32)(nx/4/256)), 256, 0, stream>>>(x, xb, nx);
  transpose_cast_kernel<<<dim3(32, 64), 256, 0, stream>>>(W_down, Wd_t, 2048, 1024);
  transpose_cast_kernel<<<dim3(32, 64), 256, 0, stream>>>(W_qr,  Wqr_t, 2048, 1024);
  transpose_cast_kernel<<<dim3(2, 64),  256, 0, stream>>>(W_kr,  Wkr_t, 2048, 64);
  transpose_cast_kernel<<<dim3(128,16), 256, 0, stream>>>(W_uKV, WuKV_t, 512, 4096);
  transpose_cast_kernel<<<dim3(64, 16), 256, 0, stream>>>(W_uQ,  WuQ_t, 512, 2048);
  transpose_cast_kernel<<<dim3(64, 64), 256, 0, stream>>>(W_out, Wout_t, 2048, 2048);
  rope_tab_kernel<<<dim3(256), 256, 0, stream>>>(ctab, stab);

  // 2) projection GEMMs
  gemm_bt_kernel<0><<<dim3(64, 8),  256, 0, stream>>>(xb, Wd_t,  b_down, down_b, 8192, 1024, 2048, 2048, 2048, 1024);
  gemm_bt_kernel<0><<<dim3(64, 8),  256, 0, stream>>>(xb, Wqr_t, b_qr,   qr_b,   8192, 1024, 2048, 2048, 2048, 1024);
  gemm_bt_kernel<0><<<dim3(64, 1),  256, 0, stream>>>(xb, Wkr_t, b_kr,   kr_b,   8192, 64,   2048, 2048, 2048, 64);
  gemm_bt_kernel<0><<<dim3(64, 32), 256, 0, stream>>>(down_b,       WuKV_t, b_uKV, vk_b, 8192, 4096, 512, 1024, 512, 4096);
  gemm_bt_kernel<0><<<dim3(64, 16), 256, 0, stream>>>(down_b + 512, WuQ_t,  b_uQ,  q_b,  8192, 2048, 512, 1024, 512, 2048);

  // 3) RoPE in place + V transpose (down_b dead -> slot5 becomes Vt)
  rope_inplace_kernel<<<dim3(16384), 256, 0, stream>>>((u32*)qr_b, ctab, stab, 9);
  rope_inplace_kernel<<<dim3(1024),  256, 0, stream>>>((u32*)kr_b, ctab, stab, 5);
  transpose_v_kernel<<<dim3(16, 64), 256, 0, stream>>>(vk_b, Vt);

  // 4) attention (writes attn_b over dead xb)
  attn_kernel<<<dim3(32, 64), 256, 0, stream>>>(q_b, qr_b, vk_b, kr_b, Vt, attn_b);

  // 5) output projection (f32 out)
  gemm_bt_kernel<1><<<dim3(64, 16), 256, 0, stream>>>(attn_b, Wout_t, b_out, out, 8192, 2048, 2048, 2048, 2048, 2048);
}

// Round 5
// 900.685 us; speedup vs baseline: 1.0292x; 1.0292x over previous
//
#include <hip/hip_runtime.h>
#include <hip/hip_bf16.h>

typedef unsigned short u16;
typedef unsigned int u32;
typedef __attribute__((ext_vector_type(4))) float f32x4;
typedef __attribute__((ext_vector_type(8))) short s16x8;

#define NHEADS 16
#define TSEQ 2048
#define BATCH 4
#define BT (BATCH*TSEQ)   // 8192 rows

__device__ __forceinline__ float bf2f(u16 v){ u32 u=((u32)v)<<16; return __builtin_bit_cast(float,u); }
__device__ __forceinline__ u16 f2bf(float f){ u32 u=__builtin_bit_cast(u32,f); u += 0x7fffu + ((u>>16)&1u); return (u16)(u>>16); }

__device__ __forceinline__ void gload16(const void* g, void* l){
  __builtin_amdgcn_global_load_lds((const __attribute__((address_space(1))) u32*)g,
                                   (__attribute__((address_space(3))) u32*)l, 16, 0, 0);
}

// ---------------- cast fp32 -> bf16 (vectorized) ----------------
__global__ void cast_bf16_kernel(const float* __restrict__ in, u16* __restrict__ out, long n){
  long i = ((long)blockIdx.x*256 + threadIdx.x)*4;
  if (i >= n) return;
  float4 v = *(const float4*)(in + i);
  ushort4 o;
  o.x = f2bf(v.x); o.y = f2bf(v.y); o.z = f2bf(v.z); o.w = f2bf(v.w);
  *(ushort4*)(out + i) = o;
}

// ---------------- transpose+cast: in[R][C] f32 -> out[C][R] bf16 ----------------
__global__ void transpose_cast_kernel(const float* __restrict__ in, u16* __restrict__ out, int R, int C){
  __shared__ float tile[32][33];
  int bc = blockIdx.x*32, br = blockIdx.y*32;
  int lx = threadIdx.x & 31, ly = threadIdx.x >> 5;   // 32x8
  #pragma unroll
  for (int i=0;i<32;i+=8)
    tile[ly+i][lx] = in[(long)(br+ly+i)*C + bc + lx];
  __syncthreads();
  #pragma unroll
  for (int i=0;i<32;i+=8)
    out[(long)(bc+ly+i)*R + br + lx] = f2bf(tile[lx][ly+i]);
}

// ---------------- RoPE tables: ctab/stab[t][32] ----------------
__global__ void rope_tab_kernel(float* __restrict__ ctab, float* __restrict__ stab){
  int idx = blockIdx.x*256 + threadIdx.x;   // 65536 = 2048*32
  int t = idx >> 5, i = idx & 31;
  float theta = expf(-(float)i * (9.210340371976184f/32.0f));   // 10000^(-i/32)
  float ang = (float)t * theta;
  float s, c;
  sincosf(ang, &s, &c);
  ctab[idx] = c; stab[idx] = s;
}

// ---------------- bias concat: [b_down(1024) | b_qr(1024) | b_kr(64) | 0-pad] ----------------
__global__ void concat_bias_kernel(const float* __restrict__ a, const float* __restrict__ b,
                                   const float* __restrict__ c, float* __restrict__ o){
  int i = blockIdx.x*256 + threadIdx.x;
  if (i >= 2176) return;
  float v = 0.f;
  if (i < 1024) v = a[i];
  else if (i < 2048) v = b[i-1024];
  else if (i < 2112) v = c[i-2048];
  o[i] = v;
}

// ---------------- RoPE in place on strided rows of u32 bf16-pairs ----------------
__global__ void rope_inplace_kernel(u32* __restrict__ buf, const float* __restrict__ ct,
                                    const float* __restrict__ st, int log2ppr, int rstride){
  long idx = (long)blockIdx.x*256 + threadIdx.x;   // total pairs = BT << log2ppr
  long row = idx >> log2ppr;
  int pp = (int)(idx & ((1<<log2ppr)-1));
  int t = (int)(row & (TSEQ-1));
  int pr = pp & 31;
  u32* p = buf + row*(long)rstride + pp;
  u32 v = *p;
  float x0 = bf2f((u16)v), x1 = bf2f((u16)(v>>16));
  float c = ct[t*32+pr], s = st[t*32+pr];
  float y0 = x0*c - x1*s;
  float y1 = x1*c + x0*s;
  *p = (u32)f2bf(y0) | ((u32)f2bf(y1)<<16);
}

// ---------------- GEMM: C[M][N] = A[M][K](bf16,lda) @ Bt[N][K]^T(bf16,ldb) + bias ----------------
// m97 structure: 128x128 tile, BK=32, 4 waves each 64x64, global_load_lds width 16.
template<int OUTF32>
__global__ __launch_bounds__(256,2) void gemm_bt_kernel(
    const u16* __restrict__ A, const u16* __restrict__ Bt, const float* __restrict__ bias,
    void* __restrict__ Cp, int M, int N, int K, int lda, int ldb, int ldc)
{
  __shared__ u16 As[128*32];
  __shared__ u16 Bs[128*32];
  const int tid = threadIdx.x;
  const int lane = tid & 63;
  const int wave = tid >> 6;
  const long bm = (long)blockIdx.x * 128;
  const long bn = (long)blockIdx.y * 128;
  const int wr = (wave>>1)*64, wc = (wave&1)*64;
  const int g = lane>>4, r15 = lane&15;

  f32x4 acc[4][4];
  #pragma unroll
  for (int m=0;m<4;m++)
    #pragma unroll
    for (int n=0;n<4;n++) acc[m][n] = (f32x4){0.f,0.f,0.f,0.f};

  const int c0 = tid, c1 = tid + 256;
  const u16* gA0 = A + (bm + (c0>>2))*lda + (c0&3)*8;
  const u16* gA1 = A + (bm + (c1>>2))*lda + (c1&3)*8;
  const u16* gB0 = Bt + (bn + (c0>>2))*ldb + (c0&3)*8;
  const u16* gB1 = Bt + (bn + (c1>>2))*ldb + (c1&3)*8;
  u16* lA0 = As + c0*8;
  u16* lA1 = As + c1*8;
  u16* lB0 = Bs + c0*8;
  u16* lB1 = Bs + c1*8;

  for (int k0 = 0; k0 < K; k0 += 32) {
    __syncthreads();
    gload16(gA0 + k0, lA0);
    gload16(gA1 + k0, lA1);
    gload16(gB0 + k0, lB0);
    gload16(gB1 + k0, lB1);
    __syncthreads();
    s16x8 af[4], bfr[4];
    #pragma unroll
    for (int m=0;m<4;m++) af[m] = *(const s16x8*)(As + (wr + m*16 + r15)*32 + g*8);
    #pragma unroll
    for (int n=0;n<4;n++) bfr[n] = *(const s16x8*)(Bs + (wc + n*16 + r15)*32 + g*8);
    #pragma unroll
    for (int m=0;m<4;m++)
      #pragma unroll
      for (int n=0;n<4;n++)
        acc[m][n] = __builtin_amdgcn_mfma_f32_16x16x32_bf16(af[m], bfr[n], acc[m][n], 0,0,0);
  }

  #pragma unroll
  for (int n=0;n<4;n++){
    long col = bn + wc + n*16 + r15;
    if (col >= N) continue;
    float bv = bias[col];
    #pragma unroll
    for (int m=0;m<4;m++){
      long row0 = bm + wr + m*16 + g*4;
      #pragma unroll
      for (int i=0;i<4;i++){
        long row = row0 + i;
        if (row < M){
          float v = acc[m][n][i] + bv;
          if (OUTF32) ((float*)Cp)[row*(long)ldc + col] = v;
          else        ((u16*)Cp)[row*(long)ldc + col] = f2bf(v);
        }
      }
    }
  }
}

// ---------------- Vt[bh][d][t] = vk_b[b,t,h*256+d] (transpose via LDS) ----------------
__global__ void transpose_v_kernel(const u16* __restrict__ vk_b, u16* __restrict__ Vt){
  __shared__ u16 tile[128][130];
  int t0 = blockIdx.x*128;
  int bh = blockIdx.y;
  int b = bh>>4, h = bh&15;
  for (int idx = threadIdx.x; idx < 128*128; idx += 256){
    int r = idx>>7, c = idx&127;
    tile[r][c] = vk_b[((long)(b*TSEQ + t0 + r))*4096 + h*256 + c];
  }
  __syncthreads();
  for (int idx = threadIdx.x; idx < 128*128; idx += 256){
    int d = idx>>7, tt = idx&127;
    Vt[((long)bh*128 + d)*TSEQ + t0 + tt] = tile[tt][d];
  }
}

// ---------------- flash attention (non-causal), 4 waves x 16 q-rows, K-tile=64 ----------------
// Async reg-staged K/V (T14), setprio around MFMA (T5), defer-max (T13).
// qrB/krB point into C1 (row stride 2112 bf16).
__global__ __launch_bounds__(256,2) void attn_kernel(
    const u16* __restrict__ q_b, const u16* __restrict__ qrB,
    const u16* __restrict__ vk_b, const u16* __restrict__ krB,
    const u16* __restrict__ Vt, u16* __restrict__ attn_b)
{
  __shared__ u16 Ks[64*192];    // swizzled: byte ^= (row&7)<<4
  __shared__ u16 Vs[128*64];    // swizzled
  __shared__ u16 Ps[4][16*64];  // per-wave, swizzled

  const int tid = threadIdx.x;
  const int lane = tid & 63;
  const int wave = tid >> 6;
  const int g = lane >> 4;
  const int r15 = lane & 15;
  const int bh = blockIdx.y;
  const int b = bh>>4, h = bh&15;
  const int q0 = blockIdx.x*64 + wave*16;

  // Q fragments hoisted to registers (A-operand: row=lane&15, k=(lane>>4)*8..+7)
  s16x8 qf[6];
  {
    const u16* qp  = q_b + ((long)b*TSEQ + q0 + r15)*2048 + h*128 + g*8;
    const u16* qrp = qrB + ((long)b*TSEQ + q0 + r15)*2112 + h*64  + g*8;
    #pragma unroll
    for (int kd=0;kd<4;kd++) qf[kd] = *(const s16x8*)(qp + kd*32);
    qf[4] = *(const s16x8*)(qrp);
    qf[5] = *(const s16x8*)(qrp + 32);
  }

  f32x4 oacc[8];
  #pragma unroll
  for (int i=0;i<8;i++) oacc[i] = (f32x4){0.f,0.f,0.f,0.f};
  float mrow[4] = {-__builtin_inff(),-__builtin_inff(),-__builtin_inff(),-__builtin_inff()};
  float lrow[4] = {0.f,0.f,0.f,0.f};

  const int krow_s = tid>>2;   // K staging: 4 threads/row, 6 chunks each
  const int kslot_s = tid&3;
  const int vrow_s = tid>>1;   // V staging: 2 threads/row, 4 chunks each
  const int vslot_s = tid&1;
  const u16* kbase = vk_b + (long)b*TSEQ*4096 + h*256 + 128 + kslot_s*8;   // + t*4096
  const u16* rbase = krB + (long)b*TSEQ*2112 + kslot_s*8;                  // + t*2112
  const long vg_base = (long)bh*128*TSEQ;
  char* KsB = (char*)Ks;
  char* VsB = (char*)Vs;
  char* PsB = (char*)(&Ps[wave][0]);

  // staging registers (tile kt+1 in flight while computing kt)
  s16x8 kreg[6], vreg[4];

  auto load_regs = [&](int kt){
    long t = (long)(kt*64 + krow_s);
    const u16* kp = kbase + t*4096;
    const u16* rp = rbase + t*2112;
    #pragma unroll
    for (int j=0;j<4;j++) kreg[j] = *(const s16x8*)(kp + j*32);
    kreg[4] = *(const s16x8*)(rp);
    kreg[5] = *(const s16x8*)(rp + 32);
    const u16* vsrc = Vt + vg_base + (long)vrow_s*TSEQ + kt*64 + vslot_s*8;
    #pragma unroll
    for (int j=0;j<4;j++) vreg[j] = *(const s16x8*)(vsrc + j*16);
  };
  auto write_lds = [&](){
    u32 base = (u32)((krow_s*24 + kslot_s)*16);
    u32 sw = (u32)((krow_s&7)<<4);
    #pragma unroll
    for (int j=0;j<6;j++)
      *(s16x8*)(KsB + ((base + j*64) ^ sw)) = kreg[j];
    u32 vbase = (u32)((vrow_s*8 + vslot_s)*16);
    u32 vsw = (u32)((vrow_s&7)<<4);
    #pragma unroll
    for (int j=0;j<4;j++)
      *(s16x8*)(VsB + ((vbase + j*32) ^ vsw)) = vreg[j];
  };

  // prologue: stage tile 0
  load_regs(0);
  write_lds();
  __syncthreads();

  for (int kt=0; kt<32; ++kt) {
    // issue next tile's global loads early — latency hides under QK+softmax+PV
    if (kt < 31) load_regs(kt+1);

    // S = Q @ K^T  (16 q-rows x 64 keys)
    f32x4 sacc[4];
    #pragma unroll
    for (int n=0;n<4;n++) sacc[n] = (f32x4){0.f,0.f,0.f,0.f};
    __builtin_amdgcn_s_setprio(1);
    #pragma unroll
    for (int kd=0; kd<6; kd++){
      #pragma unroll
      for (int n=0;n<4;n++){
        int krow = n*16 + r15;
        u32 byt = (u32)(krow*384 + kd*64 + g*16) ^ (u32)((krow&7)<<4);
        s16x8 kfr = *(const s16x8*)(KsB + byt);
        sacc[n] = __builtin_amdgcn_mfma_f32_16x16x32_bf16(qf[kd], kfr, sacc[n], 0,0,0);
      }
    }
    __builtin_amdgcn_s_setprio(0);

    const float scale = 0.08838834764831845f;  // 1/sqrt(128)
    float tmax[4];
    #pragma unroll
    for (int i=0;i<4;i++){
      float m0 = fmaxf(fmaxf(sacc[0][i],sacc[1][i]), fmaxf(sacc[2][i],sacc[3][i]));
      #pragma unroll
      for (int off=1; off<16; off<<=1) m0 = fmaxf(m0, __shfl_xor(m0, off));
      tmax[i] = m0*scale;
    }
    // defer-max (T13): only rescale when max grew by more than THR
    float grow = 0.f;
    #pragma unroll
    for (int i=0;i<4;i++) grow = fmaxf(grow, tmax[i]-mrow[i]);
    if (__any(grow > 8.0f)){
      float psc[4];
      #pragma unroll
      for (int i=0;i<4;i++){
        float mn = fmaxf(mrow[i], tmax[i]);
        psc[i] = __expf(mrow[i]-mn);
        mrow[i] = mn;
        lrow[i] *= psc[i];
      }
      #pragma unroll
      for (int nf=0;nf<8;nf++){
        f32x4 o = oacc[nf];
        o[0]*=psc[0]; o[1]*=psc[1]; o[2]*=psc[2]; o[3]*=psc[3];
        oacc[nf] = o;
      }
    }
    float rs[4] = {0.f,0.f,0.f,0.f};
    #pragma unroll
    for (int n=0;n<4;n++){
      #pragma unroll
      for (int i=0;i<4;i++){
        float p = __expf(sacc[n][i]*scale - mrow[i]);
        rs[i] += p;
        int prow = g*4+i;
        u32 pb = (u32)(prow*128 + (n*16+r15)*2) ^ (u32)((prow&7)<<4);
        *(u16*)(PsB + pb) = f2bf(p);
      }
    }
    #pragma unroll
    for (int i=0;i<4;i++){
      float rsum = rs[i];
      #pragma unroll
      for (int off=1; off<16; off<<=1) rsum += __shfl_xor(rsum, off);
      lrow[i] += rsum;
    }

    // O += P @ V   (P from per-wave LDS, V B-operand from swizzled LDS)
    __builtin_amdgcn_s_setprio(1);
    #pragma unroll
    for (int ks=0; ks<2; ks++){
      u32 pb = (u32)(r15*128 + ks*64 + g*16) ^ (u32)((r15&7)<<4);
      s16x8 pf = *(const s16x8*)(PsB + pb);
      #pragma unroll
      for (int nf=0;nf<8;nf++){
        int vrow = nf*16 + r15;
        u32 vb = (u32)(vrow*128 + ks*64 + g*16) ^ (u32)((vrow&7)<<4);
        s16x8 vf = *(const s16x8*)(VsB + vb);
        oacc[nf] = __builtin_amdgcn_mfma_f32_16x16x32_bf16(pf, vf, oacc[nf], 0,0,0);
      }
    }
    __builtin_amdgcn_s_setprio(0);

    __syncthreads();                 // all waves done reading Ks/Vs
    if (kt < 31) write_lds();        // vmcnt drained by compiler before ds_write
    __syncthreads();                 // writes visible
  }

  // epilogue: attn_b[(b*T+t)][h*128+d]
  #pragma unroll
  for (int nf=0;nf<8;nf++){
    #pragma unroll
    for (int i=0;i<4;i++){
      float v = oacc[nf][i] / lrow[i];
      long t = q0 + g*4 + i;
      attn_b[((long)b*TSEQ + t)*2048 + h*128 + nf*16 + r15] = f2bf(v);
    }
  }
}

extern "C" void kernel_launch(void* const* d_in, const int* in_sizes, int n_in,
                              void* d_out, int out_size, void* d_ws, size_t ws_size,
                              hipStream_t stream)
{
  const float* x      = (const float*)d_in[0];
  const float* W_down = (const float*)d_in[1];
  const float* b_down = (const float*)d_in[2];
  const float* W_uKV  = (const float*)d_in[3];
  const float* b_uKV  = (const float*)d_in[4];
  const float* W_uQ   = (const float*)d_in[5];
  const float* b_uQ   = (const float*)d_in[6];
  const float* W_kr   = (const float*)d_in[7];
  const float* b_kr   = (const float*)d_in[8];
  const float* W_qr   = (const float*)d_in[9];
  const float* b_qr   = (const float*)d_in[10];
  const float* W_out  = (const float*)d_in[11];
  const float* b_out  = (const float*)d_in[12];
  float* out = (float*)d_out;

  char* ws = (char*)d_ws;
  size_t off = 0;
  auto alloc = [&](size_t b)->char* { char* p = ws + off; off += (b + 255) & ~(size_t)255; return p; };

  // Arena (~193 MB) with lifetime aliasing:
  //  xb -> dead after GEMM1 -> reused as attn_b
  //  Vt lives inside d_out (f32 out written only by the last GEMM)
  u16* xb     = (u16*)alloc((size_t)BT*2048*2);      // 33.5 MB
  u16* attn_b = xb;
  u16* q_b    = (u16*)alloc((size_t)BT*2048*2);      // 33.5 MB
  u16* vk_b   = (u16*)alloc((size_t)BT*4096*2);      // 67.1 MB
  u16* C1     = (u16*)alloc((size_t)BT*2112*2);      // 34.6 MB [down|qr|kr]
  u16* W1_t   = (u16*)alloc((size_t)2176*2048*2);    // 8.9 MB (rows 2112..2175 pad)
  u16* WuKV_t = (u16*)alloc((size_t)4096*512*2);
  u16* WuQ_t  = (u16*)alloc((size_t)2048*512*2);
  u16* Wout_t = (u16*)alloc((size_t)2048*2048*2);
  float* ctab = (float*)alloc((size_t)2048*32*4);
  float* stab = (float*)alloc((size_t)2048*32*4);
  float* bias1= (float*)alloc((size_t)2176*4);
  u16* Vt     = (u16*)d_out;                         // 33.5 MB inside 67 MB d_out

  // 1) casts + transposes + tables
  long nx = (long)BT*2048;
  cast_bf16_kernel<<<dim3((u32)(nx/4/256)), 256, 0, stream>>>(x, xb, nx);
  transpose_cast_kernel<<<dim3(32, 64), 256, 0, stream>>>(W_down, W1_t,             2048, 1024);
  transpose_cast_kernel<<<dim3(32, 64), 256, 0, stream>>>(W_qr,  W1_t + 1024*2048,  2048, 1024);
  transpose_cast_kernel<<<dim3(2, 64),  256, 0, stream>>>(W_kr,  W1_t + 2048*2048,  2048, 64);
  transpose_cast_kernel<<<dim3(128,16), 256, 0, stream>>>(W_uKV, WuKV_t, 512, 4096);
  transpose_cast_kernel<<<dim3(64, 16), 256, 0, stream>>>(W_uQ,  WuQ_t, 512, 2048);
  transpose_cast_kernel<<<dim3(64, 64), 256, 0, stream>>>(W_out, Wout_t, 2048, 2048);
  rope_tab_kernel<<<dim3(256), 256, 0, stream>>>(ctab, stab);
  concat_bias_kernel<<<dim3(9), 256, 0, stream>>>(b_down, b_qr, b_kr, bias1);

  // 2) fused projection GEMM: C1 = x @ [W_down|W_qr|W_kr]  (N=2112)
  gemm_bt_kernel<0><<<dim3(64, 17), 256, 0, stream>>>(xb, W1_t, bias1, C1, 8192, 2112, 2048, 2048, 2048, 2112);
  // uKV / uQ GEMMs off cKV / cq columns of C1
  gemm_bt_kernel<0><<<dim3(64, 32), 256, 0, stream>>>(C1,       WuKV_t, b_uKV, vk_b, 8192, 4096, 512, 2112, 512, 4096);
  gemm_bt_kernel<0><<<dim3(64, 16), 256, 0, stream>>>(C1 + 512, WuQ_t,  b_uQ,  q_b,  8192, 2048, 512, 2112, 512, 2048);

  // 3) RoPE in place on C1's qr/kr columns + V transpose
  rope_inplace_kernel<<<dim3(16384), 256, 0, stream>>>((u32*)(C1 + 1024), ctab, stab, 9, 1056);
  rope_inplace_kernel<<<dim3(1024),  256, 0, stream>>>((u32*)(C1 + 2048), ctab, stab, 5, 1056);
  transpose_v_kernel<<<dim3(16, 64), 256, 0, stream>>>(vk_b, Vt);

  // 4) attention (writes attn_b over dead xb)
  attn_kernel<<<dim3(32, 64), 256, 0, stream>>>(q_b, C1 + 1024, vk_b, C1 + 2048, Vt, attn_b);

  // 5) output projection (f32 out; overwrites Vt region of d_out — Vt dead)
  gemm_bt_kernel<1><<<dim3(64, 16), 256, 0, stream>>>(attn_b, Wout_t, b_out, out, 8192, 2048, 2048, 2048, 2048, 2048);
}